// Round 7
// baseline (157.447 us; speedup 1.0000x reference)
//
#include <hip/hip_runtime.h>
#include <math.h>

#define NB 64
#define HH 512
#define WW 512
#define KK 31
#define PP 15
#define TSP 128               // output rows per block (4 x 32-row sub-strips)
#define NSP (HH / TSP)        // 4 row-bands per image -> grid 256 blocks = 1/CU
#define RING 64               // LDS ring rows (power of two >= 62-row window)
#define RMASK (RING - 1)
#define NT 1024               // 16 waves = 4 waves/SIMD at 1 block/CU
#define NWAVE (NT / 64)

typedef _Float16 f16;
typedef f16 f16x8 __attribute__((ext_vector_type(8)));
typedef f16 f16x4 __attribute__((ext_vector_type(4)));
typedef f16 f16x2 __attribute__((ext_vector_type(2)));

__device__ __forceinline__ f16x2 shfl_up2(f16x2 v, int delta) {
    int x = __shfl_up(__builtin_bit_cast(int, v), delta);
    return __builtin_bit_cast(f16x2, x);
}
__device__ __forceinline__ f16x2 shfl_dn2(f16x2 v, int delta) {
    int x = __shfl_down(__builtin_bit_cast(int, v), delta);
    return __builtin_bit_cast(f16x2, x);
}
__device__ __forceinline__ f16x2 sel2(bool c, f16x2 v) {
    f16x2 z = {(f16)0, (f16)0};
    return c ? v : z;
}

// ---- Phase 1: horizontal 31-sum of mask rows (local-tap method, 2 rows packed).
// Writes H rows into the Hs ring (slot = h & 63) and stashes the raw center-band
// mask rows as fp16 into the Ms ring so phase 2 never re-reads mask from global.
// 16 waves: pair index p = pfirst + k*16 + wave.
template<int NK, bool CHECK>
__device__ __forceinline__ void phase1_pairs(
        const float* __restrict__ mb, f16 (* __restrict__ Hs)[WW],
        f16 (* __restrict__ Ms)[WW],
        const int y0, const int pfirst, const int wave, const int lane)
{
    const int xbase = lane * 8;
    const bool lm1 = (lane >= 1);
    const bool lm2 = (lane >= 2);
    const bool lp1 = (lane <= 62);
    const bool lp2 = (lane <= 61);

    #pragma unroll
    for (int k = 0; k < NK; ++k) {
        const int p = pfirst + k * 16 + wave;
        if (CHECK && p > 30) continue;        // init call: 31 pairs over 32 slots
        const int h0  = 2 * p;                // H row index (ring slot = h&63)
        const int gy0 = y0 + h0 - PP;
        const int gy1 = gy0 + 1;

        float va[8], vb[8];
        if (gy0 >= 0 && gy0 < HH) {
            const float* row = mb + (size_t)gy0 * WW + xbase;
            const float4 u = *(const float4*)(row);
            const float4 v = *(const float4*)(row + 4);
            va[0] = u.x; va[1] = u.y; va[2] = u.z; va[3] = u.w;
            va[4] = v.x; va[5] = v.y; va[6] = v.z; va[7] = v.w;
        } else {
            #pragma unroll
            for (int j = 0; j < 8; ++j) va[j] = 0.0f;
        }
        if (gy1 >= 0 && gy1 < HH) {
            const float* row = mb + (size_t)gy1 * WW + xbase;
            const float4 u = *(const float4*)(row);
            const float4 v = *(const float4*)(row + 4);
            vb[0] = u.x; vb[1] = u.y; vb[2] = u.z; vb[3] = u.w;
            vb[4] = v.x; vb[5] = v.y; vb[6] = v.z; vb[7] = v.w;
        } else {
            #pragma unroll
            for (int j = 0; j < 8; ++j) vb[j] = 0.0f;
        }

        // stash raw center-band mask rows (yr in [0, TSP))
        const int yr0 = h0 - PP;              // gy0 - y0
        if (yr0 >= 0 && yr0 < TSP) {
            f16x8 mv;
            #pragma unroll
            for (int j = 0; j < 8; ++j) mv[j] = (f16)va[j];
            *(f16x8*)&Ms[yr0 & RMASK][xbase] = mv;
        }
        if (yr0 + 1 >= 0 && yr0 + 1 < TSP) {
            f16x8 mv;
            #pragma unroll
            for (int j = 0; j < 8; ++j) mv[j] = (f16)vb[j];
            *(f16x8*)&Ms[(yr0 + 1) & RMASK][xbase] = mv;
        }

        // in-lane inclusive prefixes (fp32)
        float sa[8], sb[8];
        sa[0] = va[0]; sb[0] = vb[0];
        #pragma unroll
        for (int j = 1; j < 8; ++j) { sa[j] = sa[j-1] + va[j]; sb[j] = sb[j-1] + vb[j]; }

        f16x2 ps[8];
        #pragma unroll
        for (int j = 0; j < 8; ++j)
            ps[j] = __builtin_bit_cast(f16x2, __builtin_amdgcn_cvt_pkrtz(sa[j], sb[j]));
        const f16x2 pT = ps[7];

        f16x2 A[7];
        #pragma unroll
        for (int j = 0; j < 7; ++j) A[j] = shfl_up2(pT - ps[j], 2);
        const f16x2 Bprev = shfl_up2(pT, 1);
        const f16x2 Cfull = shfl_dn2(pT, 1);
        f16x2 Cp[7];
        #pragma unroll
        for (int j = 0; j < 7; ++j) Cp[j] = shfl_dn2(ps[j], 2);

        f16x2 base = pT;
        base += sel2(lm1, Bprev);
        base += sel2(lp1, Cfull);

        f16x8 ha, hb;
        #pragma unroll
        for (int j = 0; j < 8; ++j) {
            f16x2 acc = base;
            if (j < 7) acc += sel2(lm2, A[j]);
            if (j > 0) acc += sel2(lp2, Cp[j-1]);
            ha[j] = acc[0];
            hb[j] = acc[1];
        }
        *(f16x8*)&Hs[h0 & RMASK][xbase] = ha;
        *(f16x8*)&Hs[(h0 + 1) & RMASK][xbase] = hb;
    }
}

// ---- Phase 2: one 32-row sub-strip; each thread owns 4 rows x 4 cols.
// mask comes from the fp16 LDS stash; only pred is read from global.
__device__ __forceinline__ void phase2_half(
        const float* __restrict__ pb,
        const f16 (* __restrict__ Hs)[WW], const f16 (* __restrict__ Ms)[WW],
        const int y0, const int r0h, const int c,
        float4& I4, float4& U4)
{
    // pred prefetch first: latency hides under the 34 LDS reads below
    float4 Pq[4];
    #pragma unroll
    for (int i = 0; i < 4; ++i)
        Pq[i] = *(const float4*)(pb + (size_t)(y0 + r0h + i) * WW + c);

    f16x4 hl4[4], he4[4];
    f16x4 accA = {(f16)0, (f16)0, (f16)0, (f16)0};
    f16x4 accB = {(f16)0, (f16)0, (f16)0, (f16)0};
    #pragma unroll
    for (int j = 0; j < 4; ++j) {            // rows r0h..r0h+3: save + accumulate
        hl4[j] = *(const f16x4*)&Hs[(r0h + j) & RMASK][c];
        accA += hl4[j];
    }
    #pragma unroll
    for (int j = 4; j < 15; ++j) accA += *(const f16x4*)&Hs[(r0h + j) & RMASK][c];
    #pragma unroll
    for (int j = 15; j < 30; ++j) accB += *(const f16x4*)&Hs[(r0h + j) & RMASK][c];
    #pragma unroll
    for (int i = 0; i < 4; ++i) he4[i] = *(const f16x4*)&Hs[(r0h + 30 + i) & RMASK][c];

    float4 B;
    B.x = (float)accA[0] + (float)accB[0];
    B.y = (float)accA[1] + (float)accB[1];
    B.z = (float)accA[2] + (float)accB[2];
    B.w = (float)accA[3] + (float)accB[3];

    const float inv2 = 1.0f / (float)(KK * KK);

    #pragma unroll
    for (int i = 0; i < 4; ++i) {
        const int yr = r0h + i;
        const f16x4 he = he4[i];
        const f16x4 hl = hl4[i];
        const f16x4 mm = *(const f16x4*)&Ms[yr & RMASK][c];
        const float4 p4 = Pq[i];
        const float m0 = (float)mm[0], m1 = (float)mm[1];
        const float m2 = (float)mm[2], m3 = (float)mm[3];

        B.x += (float)he[0]; B.y += (float)he[1]; B.z += (float)he[2]; B.w += (float)he[3];

        const float w0 = fmaf(5.0f, fabsf(fmaf(B.x, inv2, -m0)), 1.0f);
        const float w1 = fmaf(5.0f, fabsf(fmaf(B.y, inv2, -m1)), 1.0f);
        const float w2 = fmaf(5.0f, fabsf(fmaf(B.z, inv2, -m2)), 1.0f);
        const float w3 = fmaf(5.0f, fabsf(fmaf(B.w, inv2, -m3)), 1.0f);
        const float sg0 = __builtin_amdgcn_rcpf(1.0f + __expf(-p4.x));
        const float sg1 = __builtin_amdgcn_rcpf(1.0f + __expf(-p4.y));
        const float sg2 = __builtin_amdgcn_rcpf(1.0f + __expf(-p4.z));
        const float sg3 = __builtin_amdgcn_rcpf(1.0f + __expf(-p4.w));

        I4.x = fmaf(sg0 * m0, w0, I4.x);  U4.x = fmaf(sg0 + m0, w0, U4.x);
        I4.y = fmaf(sg1 * m1, w1, I4.y);  U4.y = fmaf(sg1 + m1, w1, U4.y);
        I4.z = fmaf(sg2 * m2, w2, I4.z);  U4.z = fmaf(sg2 + m2, w2, U4.z);
        I4.w = fmaf(sg3 * m3, w3, I4.w);  U4.w = fmaf(sg3 + m3, w3, U4.w);

        B.x -= (float)hl[0]; B.y -= (float)hl[1]; B.z -= (float)hl[2]; B.w -= (float)hl[3];
    }
}

// ws layout: part[0..255] = per-block inter, part[256..511] = per-block union

__global__ __launch_bounds__(NT, 4) void dice_fused_kernel(
        const float* __restrict__ pred,
        const float* __restrict__ mask,
        float* __restrict__ part) {
    const int sp = blockIdx.x;           // 0..3 row-band
    const int b  = blockIdx.y;
    const int t  = threadIdx.x;
    const int wave = t >> 6;
    const int lane = t & 63;

    __shared__ f16 Hs[RING][WW];         // 64 KB: horizontal-box-sum ring
    __shared__ f16 Ms[RING][WW];         // 64 KB: fp16 mask stash ring
    __shared__ float red[2 * NWAVE];     // ~128.1 KB total -> 1 block/CU, 16 waves

    const float* mb = mask + (size_t)b * HH * WW;
    const float* pb = pred + (size_t)b * HH * WW;
    const int y0 = sp * TSP;

    // initial fill: H rows h=0..61 (pairs 0..30 over 32 slots)
    phase1_pairs<2, true>(mb, Hs, Ms, y0, 0, wave, lane);
    __syncthreads();

    const int q = t & 127;               // col group
    const int g = t >> 7;                // 0..7 row group
    const int c = q * 4;

    float4 I4 = make_float4(0.f, 0.f, 0.f, 0.f);
    float4 U4 = make_float4(0.f, 0.f, 0.f, 0.f);

    #pragma unroll
    for (int half = 0; half < 4; ++half) {
        phase2_half(pb, Hs, Ms, y0, 32 * half + g * 4, c, I4, U4);
        __syncthreads();                 // readers done before ring overwrite
        if (half < 3) {
            // next 32 H rows: pairs 31+16*half .. 46+16*half (16 pairs, 16 waves)
            phase1_pairs<1, false>(mb, Hs, Ms, y0, 31 + 16 * half, wave, lane);
            __syncthreads();
        }
    }

    // ================= Block reduction -> per-block partials ======================
    float inter = I4.x + I4.y + I4.z + I4.w;
    float uni   = U4.x + U4.y + U4.z + U4.w;
    #pragma unroll
    for (int off = 32; off > 0; off >>= 1) {
        inter += __shfl_down(inter, off);
        uni   += __shfl_down(uni, off);
    }
    if (lane == 0) { red[wave] = inter; red[NWAVE + wave] = uni; }
    __syncthreads();
    if (t == 0) {
        float ti = 0.f, tu = 0.f;
        #pragma unroll
        for (int w2 = 0; w2 < NWAVE; ++w2) { ti += red[w2]; tu += red[NWAVE + w2]; }
        const int bid = b * NSP + sp;
        part[bid] = ti;
        part[NB * NSP + bid] = tu;
    }
}

// ---------------- Final reduction ---------------
__global__ void dice_final_kernel(const float* __restrict__ part,
                                  float* __restrict__ out) {
    const int t = threadIdx.x;  // 64 threads, one per image
    float inter = 0.0f, uni = 0.0f;
    #pragma unroll
    for (int s = 0; s < NSP; ++s) {
        inter += part[t * NSP + s];
        uni   += part[NB * NSP + t * NSP + s];
    }
    float wd = 1.0f - (2.0f * inter + 0.5f) / (uni + 0.5f);
    #pragma unroll
    for (int off = 32; off > 0; off >>= 1) wd += __shfl_down(wd, off);
    if (t == 0) out[0] = wd * (1.0f / (float)NB);
}

extern "C" void kernel_launch(void* const* d_in, const int* in_sizes, int n_in,
                              void* d_out, int out_size, void* d_ws, size_t ws_size,
                              hipStream_t stream) {
    const float* pred = (const float*)d_in[0];
    const float* mask = (const float*)d_in[1];
    float* out  = (float*)d_out;
    float* part = (float*)d_ws;   // 512 floats = 2 KB

    dim3 grid(NSP, NB);           // 4 x 64 = 256 blocks = exactly 1 per CU
    dice_fused_kernel<<<grid, NT, 0, stream>>>(pred, mask, part);
    dice_final_kernel<<<1, 64, 0, stream>>>(part, out);
}

// Round 8
// 146.621 us; speedup vs baseline: 1.0738x; 1.0738x over previous
//
#include <hip/hip_runtime.h>
#include <math.h>

#define NB 64
#define HH 512
#define WW 512
#define KK 31
#define PP 15
#define TSP 128               // output rows per block (4 x 32-row sub-strips)
#define NSP (HH / TSP)        // 4 row-bands per image -> grid 256 blocks = 1/CU
#define RING 64               // LDS ring rows (power of two >= 62-row window)
#define RMASK (RING - 1)

typedef _Float16 f16;
typedef f16 f16x8 __attribute__((ext_vector_type(8)));
typedef f16 f16x4 __attribute__((ext_vector_type(4)));
typedef f16 f16x2 __attribute__((ext_vector_type(2)));

__device__ __forceinline__ f16x2 shfl_up2(f16x2 v, int delta) {
    int x = __shfl_up(__builtin_bit_cast(int, v), delta);
    return __builtin_bit_cast(f16x2, x);
}
__device__ __forceinline__ f16x2 shfl_dn2(f16x2 v, int delta) {
    int x = __shfl_down(__builtin_bit_cast(int, v), delta);
    return __builtin_bit_cast(f16x2, x);
}
__device__ __forceinline__ f16x2 sel2(bool c, f16x2 v) {
    f16x2 z = {(f16)0, (f16)0};
    return c ? v : z;
}
// scheduling fence: loads above cannot sink below, memory ops below cannot hoist
__device__ __forceinline__ void memfence_sched() { asm volatile("" ::: "memory"); }

// ---- load 2 mask rows (pair p) into registers, zero-padded at image edges ----
__device__ __forceinline__ void load_pair(
        const float* __restrict__ mb, const int y0, const int p,
        const int xbase, float (&va)[8], float (&vb)[8])
{
    const int gy0 = y0 + 2 * p - PP;
    const int gy1 = gy0 + 1;
    if (gy0 >= 0 && gy0 < HH) {
        const float* row = mb + (size_t)gy0 * WW + xbase;
        const float4 u = *(const float4*)(row);
        const float4 v = *(const float4*)(row + 4);
        va[0] = u.x; va[1] = u.y; va[2] = u.z; va[3] = u.w;
        va[4] = v.x; va[5] = v.y; va[6] = v.z; va[7] = v.w;
    } else {
        #pragma unroll
        for (int j = 0; j < 8; ++j) va[j] = 0.0f;
    }
    if (gy1 >= 0 && gy1 < HH) {
        const float* row = mb + (size_t)gy1 * WW + xbase;
        const float4 u = *(const float4*)(row);
        const float4 v = *(const float4*)(row + 4);
        vb[0] = u.x; vb[1] = u.y; vb[2] = u.z; vb[3] = u.w;
        vb[4] = v.x; vb[5] = v.y; vb[6] = v.z; vb[7] = v.w;
    } else {
        #pragma unroll
        for (int j = 0; j < 8; ++j) vb[j] = 0.0f;
    }
}

// ---- compute H (horizontal 31-sum, local-tap method, 2 rows packed) and write
// rings: Hs slot = h&63; Ms stash for center-band rows (phase 2 mask source) ----
__device__ __forceinline__ void compute_pair(
        f16 (* __restrict__ Hs)[WW], f16 (* __restrict__ Ms)[WW],
        const int p, const int xbase, const int lane,
        const float (&va)[8], const float (&vb)[8])
{
    const bool lm1 = (lane >= 1);
    const bool lm2 = (lane >= 2);
    const bool lp1 = (lane <= 62);
    const bool lp2 = (lane <= 61);
    const int h0 = 2 * p;

    // stash raw center-band mask rows (yr in [0, TSP))
    const int yr0 = h0 - PP;
    if (yr0 >= 0 && yr0 < TSP) {
        f16x8 mv;
        #pragma unroll
        for (int j = 0; j < 8; ++j) mv[j] = (f16)va[j];
        *(f16x8*)&Ms[yr0 & RMASK][xbase] = mv;
    }
    if (yr0 + 1 >= 0 && yr0 + 1 < TSP) {
        f16x8 mv;
        #pragma unroll
        for (int j = 0; j < 8; ++j) mv[j] = (f16)vb[j];
        *(f16x8*)&Ms[(yr0 + 1) & RMASK][xbase] = mv;
    }

    float sa[8], sb[8];
    sa[0] = va[0]; sb[0] = vb[0];
    #pragma unroll
    for (int j = 1; j < 8; ++j) { sa[j] = sa[j-1] + va[j]; sb[j] = sb[j-1] + vb[j]; }

    f16x2 ps[8];
    #pragma unroll
    for (int j = 0; j < 8; ++j)
        ps[j] = __builtin_bit_cast(f16x2, __builtin_amdgcn_cvt_pkrtz(sa[j], sb[j]));
    const f16x2 pT = ps[7];

    f16x2 A[7];
    #pragma unroll
    for (int j = 0; j < 7; ++j) A[j] = shfl_up2(pT - ps[j], 2);
    const f16x2 Bprev = shfl_up2(pT, 1);
    const f16x2 Cfull = shfl_dn2(pT, 1);
    f16x2 Cp[7];
    #pragma unroll
    for (int j = 0; j < 7; ++j) Cp[j] = shfl_dn2(ps[j], 2);

    f16x2 base = pT;
    base += sel2(lm1, Bprev);
    base += sel2(lp1, Cfull);

    f16x8 ha, hb;
    #pragma unroll
    for (int j = 0; j < 8; ++j) {
        f16x2 acc = base;
        if (j < 7) acc += sel2(lm2, A[j]);
        if (j > 0) acc += sel2(lp2, Cp[j-1]);
        ha[j] = acc[0];
        hb[j] = acc[1];
    }
    *(f16x8*)&Hs[h0 & RMASK][xbase] = ha;
    *(f16x8*)&Hs[(h0 + 1) & RMASK][xbase] = hb;
}

// ---- Phase 2: one 32-row sub-strip; each thread owns 8 rows x 4 cols.
// pred prefetched up-front (pinned); mask from fp16 LDS stash. ----
__device__ __forceinline__ void phase2_half(
        const float* __restrict__ pb,
        const f16 (* __restrict__ Hs)[WW], const f16 (* __restrict__ Ms)[WW],
        const int y0, const int r0h, const int c,
        float4& I4, float4& U4)
{
    float4 Pq[8];
    #pragma unroll
    for (int i = 0; i < 8; ++i)
        Pq[i] = *(const float4*)(pb + (size_t)(y0 + r0h + i) * WW + c);
    memfence_sched();                       // pin pred loads above the warm-up

    f16x4 hl8[8], he8[8];
    f16x4 accA = {(f16)0, (f16)0, (f16)0, (f16)0};
    f16x4 accB = {(f16)0, (f16)0, (f16)0, (f16)0};
    #pragma unroll
    for (int j = 0; j < 8; ++j) {           // rows r0h..r0h+7: save + accumulate
        hl8[j] = *(const f16x4*)&Hs[(r0h + j) & RMASK][c];
        accA += hl8[j];
    }
    #pragma unroll
    for (int j = 8; j < 15; ++j) accA += *(const f16x4*)&Hs[(r0h + j) & RMASK][c];
    #pragma unroll
    for (int j = 15; j < 30; ++j) accB += *(const f16x4*)&Hs[(r0h + j) & RMASK][c];
    #pragma unroll
    for (int i = 0; i < 8; ++i) he8[i] = *(const f16x4*)&Hs[(r0h + 30 + i) & RMASK][c];

    float4 B;
    B.x = (float)accA[0] + (float)accB[0];
    B.y = (float)accA[1] + (float)accB[1];
    B.z = (float)accA[2] + (float)accB[2];
    B.w = (float)accA[3] + (float)accB[3];

    const float inv2 = 1.0f / (float)(KK * KK);

    #pragma unroll
    for (int i = 0; i < 8; ++i) {
        const int yr = r0h + i;
        const f16x4 he = he8[i];
        const f16x4 hl = hl8[i];
        const f16x4 mm = *(const f16x4*)&Ms[yr & RMASK][c];
        const float4 p4 = Pq[i];
        const float m0 = (float)mm[0], m1 = (float)mm[1];
        const float m2 = (float)mm[2], m3 = (float)mm[3];

        B.x += (float)he[0]; B.y += (float)he[1]; B.z += (float)he[2]; B.w += (float)he[3];

        const float w0 = fmaf(5.0f, fabsf(fmaf(B.x, inv2, -m0)), 1.0f);
        const float w1 = fmaf(5.0f, fabsf(fmaf(B.y, inv2, -m1)), 1.0f);
        const float w2 = fmaf(5.0f, fabsf(fmaf(B.z, inv2, -m2)), 1.0f);
        const float w3 = fmaf(5.0f, fabsf(fmaf(B.w, inv2, -m3)), 1.0f);
        const float sg0 = __builtin_amdgcn_rcpf(1.0f + __expf(-p4.x));
        const float sg1 = __builtin_amdgcn_rcpf(1.0f + __expf(-p4.y));
        const float sg2 = __builtin_amdgcn_rcpf(1.0f + __expf(-p4.z));
        const float sg3 = __builtin_amdgcn_rcpf(1.0f + __expf(-p4.w));

        I4.x = fmaf(sg0 * m0, w0, I4.x);  U4.x = fmaf(sg0 + m0, w0, U4.x);
        I4.y = fmaf(sg1 * m1, w1, I4.y);  U4.y = fmaf(sg1 + m1, w1, U4.y);
        I4.z = fmaf(sg2 * m2, w2, I4.z);  U4.z = fmaf(sg2 + m2, w2, U4.z);
        I4.w = fmaf(sg3 * m3, w3, I4.w);  U4.w = fmaf(sg3 + m3, w3, U4.w);

        B.x -= (float)hl[0]; B.y -= (float)hl[1]; B.z -= (float)hl[2]; B.w -= (float)hl[3];
    }
}

// ws layout: part[0..255] = per-block inter, part[256..511] = per-block union

// min-waves 2 -> 256-VGPR budget: room for prefetch liveness, no spill.
// Occupancy is LDS-capped at 1 block/CU (128.5 KB) regardless.
__global__ __launch_bounds__(512, 2) void dice_fused_kernel(
        const float* __restrict__ pred,
        const float* __restrict__ mask,
        float* __restrict__ part) {
    const int sp = blockIdx.x;           // 0..3 row-band
    const int b  = blockIdx.y;
    const int t  = threadIdx.x;
    const int wave = t >> 6;
    const int lane = t & 63;
    const int xbase = lane * 8;

    __shared__ f16 Hs[RING][WW];         // 64 KB: horizontal-box-sum ring
    __shared__ f16 Ms[RING][WW];         // 64 KB: fp16 mask stash ring
    __shared__ float red[16];

    const float* mb = mask + (size_t)b * HH * WW;
    const float* pb = pred + (size_t)b * HH * WW;
    const int y0 = sp * TSP;

    // initial fill: H rows 0..61 (pairs 0..30 over 8 waves x 4 k-slots)
    #pragma unroll
    for (int k = 0; k < 4; ++k) {
        const int p = k * 8 + wave;
        if (p > 30) continue;
        float va[8], vb[8];
        load_pair(mb, y0, p, xbase, va, vb);
        compute_pair(Hs, Ms, p, xbase, lane, va, vb);
    }
    __syncthreads();

    const int q = t & 127;               // col group
    const int g = t >> 7;                // 0..3 row group (8 rows each)
    const int c = q * 4;

    float4 I4 = make_float4(0.f, 0.f, 0.f, 0.f);
    float4 U4 = make_float4(0.f, 0.f, 0.f, 0.f);

    float va0[8], vb0[8], va1[8], vb1[8];    // refill stage registers (2 pairs)

    #pragma unroll
    for (int half = 0; half < 4; ++half) {
        const int pf = 31 + 16 * half + wave;
        if (half < 3) {
            // T14 split: issue refill global loads now; latency hides under phase 2
            load_pair(mb, y0, pf,     xbase, va0, vb0);
            load_pair(mb, y0, pf + 8, xbase, va1, vb1);
            memfence_sched();            // pin loads above phase-2
        }
        phase2_half(pb, Hs, Ms, y0, 32 * half + g * 8, c, I4, U4);
        __syncthreads();                 // ring readers done before overwrite
        if (half < 3) {
            compute_pair(Hs, Ms, pf,     xbase, lane, va0, vb0);
            compute_pair(Hs, Ms, pf + 8, xbase, lane, va1, vb1);
            __syncthreads();
        }
    }

    // ================= Block reduction -> per-block partials ======================
    float inter = I4.x + I4.y + I4.z + I4.w;
    float uni   = U4.x + U4.y + U4.z + U4.w;
    #pragma unroll
    for (int off = 32; off > 0; off >>= 1) {
        inter += __shfl_down(inter, off);
        uni   += __shfl_down(uni, off);
    }
    if (lane == 0) { red[wave] = inter; red[8 + wave] = uni; }
    __syncthreads();
    if (t == 0) {
        float ti = 0.f, tu = 0.f;
        #pragma unroll
        for (int w2 = 0; w2 < 8; ++w2) { ti += red[w2]; tu += red[8 + w2]; }
        const int bid = b * NSP + sp;
        part[bid] = ti;
        part[NB * NSP + bid] = tu;
    }
}

// ---------------- Final reduction ---------------
__global__ void dice_final_kernel(const float* __restrict__ part,
                                  float* __restrict__ out) {
    const int t = threadIdx.x;  // 64 threads, one per image
    float inter = 0.0f, uni = 0.0f;
    #pragma unroll
    for (int s = 0; s < NSP; ++s) {
        inter += part[t * NSP + s];
        uni   += part[NB * NSP + t * NSP + s];
    }
    float wd = 1.0f - (2.0f * inter + 0.5f) / (uni + 0.5f);
    #pragma unroll
    for (int off = 32; off > 0; off >>= 1) wd += __shfl_down(wd, off);
    if (t == 0) out[0] = wd * (1.0f / (float)NB);
}

extern "C" void kernel_launch(void* const* d_in, const int* in_sizes, int n_in,
                              void* d_out, int out_size, void* d_ws, size_t ws_size,
                              hipStream_t stream) {
    const float* pred = (const float*)d_in[0];
    const float* mask = (const float*)d_in[1];
    float* out  = (float*)d_out;
    float* part = (float*)d_ws;   // 512 floats = 2 KB

    dim3 grid(NSP, NB);           // 4 x 64 = 256 blocks = exactly 1 per CU
    dice_fused_kernel<<<grid, 512, 0, stream>>>(pred, mask, part);
    dice_final_kernel<<<1, 64, 0, stream>>>(part, out);
}

// Round 9
// 145.238 us; speedup vs baseline: 1.0841x; 1.0095x over previous
//
#include <hip/hip_runtime.h>
#include <math.h>

#define NB 64
#define HH 512
#define WW 512
#define KK 31
#define PP 15
#define TSP 128               // output rows per block
#define CB 256                // output cols per block
#define NSTR 8                // strips per image: 4 row-bands x 2 col-halves
#define RING 64               // LDS ring rows (>= 62-row window)
#define RMASK (RING - 1)

typedef _Float16 f16;
typedef f16 f16x8 __attribute__((ext_vector_type(8)));
typedef f16 f16x2 __attribute__((ext_vector_type(2)));

__device__ __forceinline__ f16x2 shfl_up2(f16x2 v, int delta) {
    int x = __shfl_up(__builtin_bit_cast(int, v), delta);
    return __builtin_bit_cast(f16x2, x);
}
__device__ __forceinline__ f16x2 shfl_dn2(f16x2 v, int delta) {
    int x = __shfl_down(__builtin_bit_cast(int, v), delta);
    return __builtin_bit_cast(f16x2, x);
}

// ---- load 2 mask rows (pair p) of this block's 288-col window into registers.
// Zero-padding at image edges lives in the DATA (halo lanes), so the local-tap
// compute needs no lane-edge masks.  Only lanes 0..35 are active.
__device__ __forceinline__ void load_pair(
        const float* __restrict__ mb, const int y0, const int p,
        const int xg, const bool lact, float (&va)[8], float (&vb)[8])
{
    const int gy0 = y0 + 2 * p - PP;
    const int gy1 = gy0 + 1;
    if (lact && gy0 >= 0 && gy0 < HH) {
        const float* row = mb + (size_t)gy0 * WW + xg;
        const float4 u = *(const float4*)(row);
        const float4 v = *(const float4*)(row + 4);
        va[0] = u.x; va[1] = u.y; va[2] = u.z; va[3] = u.w;
        va[4] = v.x; va[5] = v.y; va[6] = v.z; va[7] = v.w;
    } else {
        #pragma unroll
        for (int j = 0; j < 8; ++j) va[j] = 0.0f;
    }
    if (lact && gy1 >= 0 && gy1 < HH) {
        const float* row = mb + (size_t)gy1 * WW + xg;
        const float4 u = *(const float4*)(row);
        const float4 v = *(const float4*)(row + 4);
        vb[0] = u.x; vb[1] = u.y; vb[2] = u.z; vb[3] = u.w;
        vb[4] = v.x; vb[5] = v.y; vb[6] = v.z; vb[7] = v.w;
    } else {
        #pragma unroll
        for (int j = 0; j < 8; ++j) vb[j] = 0.0f;
    }
}

// ---- horizontal 31-sum (local-tap, 2 rows packed in f16x2) + ring writes.
// Lane l covers cols xg..xg+7 (xg = c0-16+8l); only lanes 2..33 store (the
// 256 center cols).  Halo lanes carry neighbor data or image-edge zeros.
__device__ __forceinline__ void compute_pair(
        f16 (* __restrict__ Hs)[CB], f16 (* __restrict__ Ms)[CB],
        const int p, const int cl, const bool lstore,
        const float (&va)[8], const float (&vb)[8])
{
    const int h0 = 2 * p;

    // stash raw center-band mask rows (yr in [0, TSP))
    const int yr0 = h0 - PP;
    if (lstore && yr0 >= 0 && yr0 < TSP) {
        f16x8 mv;
        #pragma unroll
        for (int j = 0; j < 8; ++j) mv[j] = (f16)va[j];
        *(f16x8*)&Ms[yr0 & RMASK][cl] = mv;
    }
    if (lstore && yr0 + 1 >= 0 && yr0 + 1 < TSP) {
        f16x8 mv;
        #pragma unroll
        for (int j = 0; j < 8; ++j) mv[j] = (f16)vb[j];
        *(f16x8*)&Ms[(yr0 + 1) & RMASK][cl] = mv;
    }

    float sa[8], sb[8];
    sa[0] = va[0]; sb[0] = vb[0];
    #pragma unroll
    for (int j = 1; j < 8; ++j) { sa[j] = sa[j-1] + va[j]; sb[j] = sb[j-1] + vb[j]; }

    f16x2 ps[8];
    #pragma unroll
    for (int j = 0; j < 8; ++j)
        ps[j] = __builtin_bit_cast(f16x2, __builtin_amdgcn_cvt_pkrtz(sa[j], sb[j]));
    const f16x2 pT = ps[7];

    // window = suffix(l-2, j+1..7) + T(l-1) + T(l) + T(l+1) + prefix(l+2, 0..j-1)
    f16x2 A[7];
    #pragma unroll
    for (int j = 0; j < 7; ++j) A[j] = shfl_up2(pT - ps[j], 2);
    const f16x2 Bprev = shfl_up2(pT, 1);
    const f16x2 Cfull = shfl_dn2(pT, 1);
    f16x2 Cp[7];
    #pragma unroll
    for (int j = 0; j < 7; ++j) Cp[j] = shfl_dn2(ps[j], 2);

    const f16x2 base = pT + Bprev + Cfull;

    f16x8 ha, hb;
    #pragma unroll
    for (int j = 0; j < 8; ++j) {
        f16x2 acc = base;
        if (j < 7) acc += A[j];
        if (j > 0) acc += Cp[j-1];
        ha[j] = acc[0];
        hb[j] = acc[1];
    }
    if (lstore) {
        *(f16x8*)&Hs[h0 & RMASK][cl] = ha;
        *(f16x8*)&Hs[(h0 + 1) & RMASK][cl] = hb;
    }
}

// ---- Phase 2: one 32-row sub-strip; each thread owns 8 rows x 2 cols.
// mask from fp16 LDS stash; only pred read from global (float2).
__device__ __forceinline__ void phase2_half(
        const float* __restrict__ pb,
        const f16 (* __restrict__ Hs)[CB], const f16 (* __restrict__ Ms)[CB],
        const int y0, const int r0h, const int cl2, const int cg,
        float& inter, float& uni)
{
    float2 Pq[8];
    #pragma unroll
    for (int i = 0; i < 8; ++i)
        Pq[i] = *(const float2*)(pb + (size_t)(y0 + r0h + i) * WW + cg);

    f16x2 hl8[8], he8[8];
    f16x2 accA = {(f16)0, (f16)0};
    f16x2 accB = {(f16)0, (f16)0};
    #pragma unroll
    for (int j = 0; j < 8; ++j) {           // rows r0h..r0h+7: save + accumulate
        hl8[j] = *(const f16x2*)&Hs[(r0h + j) & RMASK][cl2];
        accA += hl8[j];
    }
    #pragma unroll
    for (int j = 8; j < 15; ++j) accA += *(const f16x2*)&Hs[(r0h + j) & RMASK][cl2];
    #pragma unroll
    for (int j = 15; j < 30; ++j) accB += *(const f16x2*)&Hs[(r0h + j) & RMASK][cl2];
    #pragma unroll
    for (int i = 0; i < 8; ++i) he8[i] = *(const f16x2*)&Hs[(r0h + 30 + i) & RMASK][cl2];

    float Bx = (float)accA[0] + (float)accB[0];
    float By = (float)accA[1] + (float)accB[1];

    const float inv2 = 1.0f / (float)(KK * KK);

    #pragma unroll
    for (int i = 0; i < 8; ++i) {
        const int yr = r0h + i;
        const f16x2 he = he8[i];
        const f16x2 hl = hl8[i];
        const f16x2 mm = *(const f16x2*)&Ms[yr & RMASK][cl2];
        const float2 p2 = Pq[i];
        const float m0 = (float)mm[0], m1 = (float)mm[1];

        Bx += (float)he[0]; By += (float)he[1];

        const float w0 = fmaf(5.0f, fabsf(fmaf(Bx, inv2, -m0)), 1.0f);
        const float w1 = fmaf(5.0f, fabsf(fmaf(By, inv2, -m1)), 1.0f);
        const float sg0 = __builtin_amdgcn_rcpf(1.0f + __expf(-p2.x));
        const float sg1 = __builtin_amdgcn_rcpf(1.0f + __expf(-p2.y));

        inter = fmaf(sg0 * m0, w0, inter);  uni = fmaf(sg0 + m0, w0, uni);
        inter = fmaf(sg1 * m1, w1, inter);  uni = fmaf(sg1 + m1, w1, uni);

        Bx -= (float)hl[0]; By -= (float)hl[1];
    }
}

// ws layout: part[0..511] = per-block inter, part[512..1023] = per-block union

// 64.1 KB LDS -> 2 blocks/CU (160 KB pool); min-waves 4 -> VGPR cap 128 so
// 16 waves/CU stay resident (r7 lesson: budget + rows/thread both matter).
__global__ __launch_bounds__(512, 4) void dice_fused_kernel(
        const float* __restrict__ pred,
        const float* __restrict__ mask,
        float* __restrict__ part) {
    const int bi = blockIdx.x;           // 0..7: band*2 + col-half
    const int b  = blockIdx.y;
    const int sp = bi >> 1;
    const int c0 = (bi & 1) * CB;
    const int t  = threadIdx.x;
    const int wave = t >> 6;
    const int lane = t & 63;

    __shared__ f16 Hs[RING][CB];         // 32 KB: horizontal-box-sum ring
    __shared__ f16 Ms[RING][CB];         // 32 KB: fp16 mask stash ring
    __shared__ float red[16];

    const float* mb = mask + (size_t)b * HH * WW;
    const float* pb = pred + (size_t)b * HH * WW;
    const int y0 = sp * TSP;

    // phase-1 lane geometry: 288-col window [c0-16, c0+272), 8 cols/lane, 36 lanes
    const int xg = c0 - 16 + lane * 8;               // global col of lane chunk
    const bool lact   = (lane < 36) && (xg >= 0) && (xg < WW);
    const bool lstore = (lane >= 2) && (lane <= 33); // center 256 cols
    const int  clp1   = (lane - 2) * 8;              // local col for p1 stores

    // initial fill: H rows 0..61 (pairs 0..30 over 8 waves x 4 k-slots)
    #pragma unroll
    for (int k = 0; k < 4; ++k) {
        const int p = k * 8 + wave;
        if (p > 30) continue;
        float va[8], vb[8];
        load_pair(mb, y0, p, xg, lact, va, vb);
        compute_pair(Hs, Ms, p, clp1, lstore, va, vb);
    }
    __syncthreads();

    // phase-2 geometry: 128 col-groups (2 cols) x 4 row-groups (8 rows)
    const int q  = t & 127;
    const int g  = t >> 7;               // 0..3
    const int cl2 = q * 2;               // local col
    const int cg  = c0 + cl2;            // global col (pred)

    float inter = 0.0f, uni = 0.0f;

    #pragma unroll
    for (int half = 0; half < 4; ++half) {
        phase2_half(pb, Hs, Ms, y0, 32 * half + g * 8, cl2, cg, inter, uni);
        __syncthreads();                 // ring readers done before overwrite
        if (half < 3) {
            const int pf = 31 + 16 * half + wave;
            float va[8], vb[8];
            load_pair(mb, y0, pf, xg, lact, va, vb);
            compute_pair(Hs, Ms, pf, clp1, lstore, va, vb);
            load_pair(mb, y0, pf + 8, xg, lact, va, vb);
            compute_pair(Hs, Ms, pf + 8, clp1, lstore, va, vb);
            __syncthreads();
        }
    }

    // ================= Block reduction -> per-block partials ======================
    #pragma unroll
    for (int off = 32; off > 0; off >>= 1) {
        inter += __shfl_down(inter, off);
        uni   += __shfl_down(uni, off);
    }
    if (lane == 0) { red[wave] = inter; red[8 + wave] = uni; }
    __syncthreads();
    if (t == 0) {
        float ti = 0.f, tu = 0.f;
        #pragma unroll
        for (int w2 = 0; w2 < 8; ++w2) { ti += red[w2]; tu += red[8 + w2]; }
        const int bid = b * NSTR + bi;
        part[bid] = ti;
        part[NB * NSTR + bid] = tu;
    }
}

// ---------------- Final reduction ---------------
__global__ void dice_final_kernel(const float* __restrict__ part,
                                  float* __restrict__ out) {
    const int t = threadIdx.x;  // 64 threads, one per image
    float inter = 0.0f, uni = 0.0f;
    #pragma unroll
    for (int s = 0; s < NSTR; ++s) {
        inter += part[t * NSTR + s];
        uni   += part[NB * NSTR + t * NSTR + s];
    }
    float wd = 1.0f - (2.0f * inter + 0.5f) / (uni + 0.5f);
    #pragma unroll
    for (int off = 32; off > 0; off >>= 1) wd += __shfl_down(wd, off);
    if (t == 0) out[0] = wd * (1.0f / (float)NB);
}

extern "C" void kernel_launch(void* const* d_in, const int* in_sizes, int n_in,
                              void* d_out, int out_size, void* d_ws, size_t ws_size,
                              hipStream_t stream) {
    const float* pred = (const float*)d_in[0];
    const float* mask = (const float*)d_in[1];
    float* out  = (float*)d_out;
    float* part = (float*)d_ws;   // 1024 floats = 4 KB

    dim3 grid(NSTR, NB);          // 8 x 64 = 512 blocks = 2 per CU
    dice_fused_kernel<<<grid, 512, 0, stream>>>(pred, mask, part);
    dice_final_kernel<<<1, 64, 0, stream>>>(part, out);
}